// Round 6
// baseline (605.802 us; speedup 1.0000x reference)
//
#include <hip/hip_runtime.h>
#include <stdint.h>

// Shapes (fixed by the problem)
#define Bn 256
#define Un 128
#define Pn 64
#define Hn 768
#define Ototal 192   // 128 row-logit outputs + 64 col-logit outputs
#define KC 16        // split-K chunks in B-part (K=8192 -> 512 each)
#define NBLK 512     // grid: exactly co-resident (2 blocks/CU on 256 CUs)

#define LDU 40       // A-part LDS row stride (ushorts): 80B = 5*16
#define LDB 72       // B-part LDS row stride (ushorts): 144B = 9*16

typedef short s4v __attribute__((ext_vector_type(4)));
typedef short s8v __attribute__((ext_vector_type(8)));
typedef float f4v __attribute__((ext_vector_type(4)));

__device__ __forceinline__ short f2bf(float x) {
  union { float f; uint32_t u; } c; c.f = x;
  uint32_t r = (c.u + 0x7fffu + ((c.u >> 16) & 1u)) >> 16;  // RNE
  return (short)(r & 0xffffu);
}

__device__ __forceinline__ float dot4(float4 v) {
  return v.x * v.x + v.y * v.y + v.z * v.z + v.w * v.w;
}

// Device-wide arrival barrier. Safe: grid is exactly co-resident
// (NBLK=512 blocks, 2/CU guaranteed by launch_bounds + 33KB LDS).
// Release: per-thread threadfence + block barrier, leader does agent-scope
// acq_rel add; acquire: leader's acquire spin invalidates its CU's L1 +
// XCD L2 (every block has a leader -> every CU covered).
__device__ __forceinline__ void gbar(unsigned* c, int t) {
  __threadfence();
  __syncthreads();
  if (t == 0) {
    __hip_atomic_fetch_add(c, 1u, __ATOMIC_ACQ_REL, __HIP_MEMORY_SCOPE_AGENT);
    while (__hip_atomic_load(c, __ATOMIC_ACQUIRE, __HIP_MEMORY_SCOPE_AGENT)
           < (unsigned)NBLK)
      __builtin_amdgcn_s_sleep(8);
  }
  __syncthreads();
  __threadfence();
}

// ---------------------------------------------------------------------------
// Single fused kernel: W-pack + phaseA (round-0 verbatim structure, the only
// one that measured 65.7us) + global barrier + phaseB + barrier + phaseC.
// Purpose of this round: eliminate ALL intermediate launches so the constant
// ~140us residual (total - phaseA, invariant over 6 measurements) is
// attributed: graph/launch overhead (-> disappears) vs real B/C time
// (-> shows up in this kernel's own dur_us).
// ---------------------------------------------------------------------------
__global__ void __launch_bounds__(512, 4) mega(
    const float* __restrict__ utt, const float* __restrict__ ph,
    const float* __restrict__ w_utt, const float* __restrict__ w_ph,
    const float* __restrict__ b_utt, const float* __restrict__ b_ph,
    ushort* __restrict__ Cbf, ushort* __restrict__ Wbf,
    float* __restrict__ partial, float* __restrict__ out,
    unsigned* __restrict__ ctr) {
  __shared__ __align__(16) char smem[33536];  // union: convW 33024 / A 10752 / B 18432
  const int bx = blockIdx.x;
  const int t = threadIdx.x;
  const int w = t >> 6, l = t & 63;
  const f4v zero4 = {0.f, 0.f, 0.f, 0.f};

  // ---- W-pack: all 512 blocks convert a 2048-elem slice of w_utt ----
  {
    int base = bx * 2048 + t * 4;               // covers 128*8192 exactly
    float4 v = *(const float4*)(w_utt + base);
    s4v o = { f2bf(v.x), f2bf(v.y), f2bf(v.z), f2bf(v.w) };
    *(s4v*)&Wbf[base] = o;
  }
  // blocks 0..63: w_ph transpose W'[128+oc][i*64+j] = w_ph[oc,j,i] via LDS tile
  if (bx < 64) {
    float* tile = (float*)smem;                 // [j][i] 64 x 129 (+1 pad)
    const float* src = w_ph + (size_t)bx * 8192;
#pragma unroll
    for (int itr = 0; itr < 4; ++itr) {
      int idx = itr * 2048 + t * 4;
      int j = idx >> 7, i = idx & 127;
      float4 v = *(const float4*)(src + idx);   // coalesced 16B
      tile[j * 129 + i + 0] = v.x;
      tile[j * 129 + i + 1] = v.y;
      tile[j * 129 + i + 2] = v.z;
      tile[j * 129 + i + 3] = v.w;
    }
    __syncthreads();
    const size_t obase = (size_t)(128 + bx) * 8192;
#pragma unroll
    for (int itr = 0; itr < 4; ++itr) {
      int k = itr * 2048 + t * 4;               // k = i*64 + j
      int i = k >> 6, j = k & 63;
      s4v o4 = { f2bf(tile[(j + 0) * 129 + i]),
                 f2bf(tile[(j + 1) * 129 + i]),
                 f2bf(tile[(j + 2) * 129 + i]),
                 f2bf(tile[(j + 3) * 129 + i]) };
      *(s4v*)&Wbf[obase + k] = o4;
    }
    __syncthreads();                            // WAR: smem reused by A-part
  }

  // ---- A-part: round-0 phaseA, transplanted verbatim (65.7us proven) ----
  {
    short* uA = (short*)smem;                   // 64*LDU shorts = 5120 B
    short* pB = (short*)(smem + 5120);          // 5120 B
    float* s_inu = (float*)(smem + 10240);
    float* s_inp = (float*)(smem + 10496);

    const int b = bx >> 1, half = bx & 1;
    const int r  = t >> 3;
    const int cc = (t & 7) * 4;

    const size_t rstride = (size_t)Bn * Hn;
    const float* ubase = utt + (size_t)b * Hn + (size_t)(half * 64 + r) * rstride + cc;
    const float* pbase = ph  + (size_t)b * Hn + (size_t)r * rstride + cc;

    float4 ru = *(const float4*)ubase;
    float4 rp = *(const float4*)pbase;

    float ssu = 0.f, ssp = 0.f;
    f4v acc0 = zero4, acc1 = zero4;

    const int m  = l & 15;
    const int ko = (l >> 4) * 8;
    const int it = w & 3;
    const int jp = w >> 2;
    const int lw = r * LDU + cc;
    const short* ab = &uA[(it * 16 + m) * LDU + ko];
    const short* bb = &pB[(jp * 32 + m) * LDU + ko];

    for (int c = 0; c < 24; ++c) {
      __syncthreads();
      float4 a = ru, p0 = rp;
      ssu += dot4(a);
      ssp += dot4(p0);
      s4v au = { f2bf(a.x),  f2bf(a.y),  f2bf(a.z),  f2bf(a.w)  };
      s4v pp = { f2bf(p0.x), f2bf(p0.y), f2bf(p0.z), f2bf(p0.w) };
      *(s4v*)&uA[lw] = au;
      *(s4v*)&pB[lw] = pp;
      __syncthreads();
      if (c < 23) {
        ru = *(const float4*)(ubase + (c + 1) * 32);
        rp = *(const float4*)(pbase + (c + 1) * 32);
      }
      s8v af  = *(const s8v*)ab;
      s8v bf0 = *(const s8v*)bb;
      s8v bf1 = *(const s8v*)(bb + 16 * LDU);
      acc0 = __builtin_amdgcn_mfma_f32_16x16x32_bf16(af, bf0, acc0, 0, 0, 0);
      acc1 = __builtin_amdgcn_mfma_f32_16x16x32_bf16(af, bf1, acc1, 0, 0, 0);
    }

    ssu += __shfl_xor(ssu, 4); ssu += __shfl_xor(ssu, 2); ssu += __shfl_xor(ssu, 1);
    ssp += __shfl_xor(ssp, 4); ssp += __shfl_xor(ssp, 2); ssp += __shfl_xor(ssp, 1);
    if ((t & 7) == 0) {
      s_inu[r] = 1.f / fmaxf(sqrtf(ssu), 1e-8f);
      s_inp[r] = 1.f / fmaxf(sqrtf(ssp), 1e-8f);
    }
    __syncthreads();

    // D layout (verified m89/m91): col = lane&15, row = (lane>>4)*4 + reg
    const int cl = l & 15;
    const int rq = (l >> 4) * 4;
#pragma unroll
    for (int jt = 0; jt < 2; ++jt) {
      int j = jp * 32 + jt * 16 + cl;
      float sj = s_inp[j];
      f4v a = (jt == 0) ? acc0 : acc1;
#pragma unroll
      for (int rr = 0; rr < 4; ++rr) {
        int il = it * 16 + rq + rr;
        float v = a[rr] * s_inu[il] * sj;
        Cbf[((size_t)b * Un + half * 64 + il) * Pn + j] = (ushort)f2bf(v);
      }
    }
  }

  gbar(ctr + 0, t);   // Cbf + Wbf complete, visible device-wide

  // ---- B-part: logits GEMM, 192 active blocks, 512 threads each ----
  if (bx < KC * 12) {
    const int kc = bx & 15, mt = (bx >> 4) & 3, nt = bx >> 6;
    short* Ab = (short*)smem;                   // 64*LDB shorts = 9216 B
    short* Bb = (short*)(smem + 9216);          // 9216 B

    // staging: waves 0-3 stage A (Cbf), waves 4-7 stage B (Wbf)
    const int sB  = t >> 8;                     // 0 = A-stager, 1 = B-stager
    const int tb  = t & 255;
    const int row = tb >> 2;                    // 0..63
    const int k16 = (tb & 3) * 16;
    const ushort* G = (sB ? Wbf + (size_t)(nt * 64 + row) * 8192
                          : Cbf + (size_t)(mt * 64 + row) * 8192) + kc * 512 + k16;
    short* S = (sB ? Bb : Ab) + row * LDB + k16;

    const int m  = l & 15;
    const int ko = (l >> 4) * 8;
    const int mtile = w & 3;                    // wave -> 16-row m-tile
    const int jh    = w >> 2;                   // wave -> 32-col j-half
    f4v acc[2] = {zero4, zero4};

    for (int c = 0; c < 8; ++c) {
      s8v v0 = *(const s8v*)(G + c * 64);
      s8v v1 = *(const s8v*)(G + c * 64 + 8);
      __syncthreads();
      *(s8v*)S = v0;
      *(s8v*)(S + 8) = v1;
      __syncthreads();
#pragma unroll
      for (int ks = 0; ks < 2; ++ks) {
        s8v af = *(const s8v*)&Ab[(16 * mtile + m) * LDB + ks * 32 + ko];
#pragma unroll
        for (int jt = 0; jt < 2; ++jt) {
          s8v bf = *(const s8v*)&Bb[(jh * 32 + jt * 16 + m) * LDB + ks * 32 + ko];
          acc[jt] = __builtin_amdgcn_mfma_f32_16x16x32_bf16(af, bf, acc[jt], 0, 0, 0);
        }
      }
    }

    const int rq = (l >> 4) * 4;
#pragma unroll
    for (int jt = 0; jt < 2; ++jt) {
      int og = nt * 64 + jh * 32 + jt * 16 + (l & 15);
#pragma unroll
      for (int rr = 0; rr < 4; ++rr) {
        int bg = mt * 64 + mtile * 16 + rq + rr;
        partial[((size_t)kc * Bn + bg) * Ototal + og] = acc[jt][rr];
      }
    }
  }

  gbar(ctr + 1, t);   // partial complete, visible device-wide

  // ---- C-part: split-K reduce + bias + dual softmax, 256 active blocks ----
  if (bx < Bn) {
    float* red = (float*)smem;                  // 3 floats (after gbar sync)
    const bool act = t < Ototal;                // waves 3..7 idle but barrier
    float v = 0.f, e = 0.f;
    if (act) {
#pragma unroll
      for (int kc = 0; kc < KC; ++kc)
        v += partial[((size_t)kc * Bn + bx) * Ototal + t];
      v += (t < Un) ? b_utt[t] : b_ph[t - Un];
    }
    float mx = v;
    for (int o = 32; o >= 1; o >>= 1) mx = fmaxf(mx, __shfl_xor(mx, o));
    if (act && l == 0) red[w] = mx;
    __syncthreads();
    float gmax = 0.f;
    if (act) {
      gmax = (t < Un) ? fmaxf(red[0], red[1]) : red[2];
      e = expf(v - gmax);
    }
    float s = act ? e : 0.f;
    for (int o = 32; o >= 1; o >>= 1) s += __shfl_xor(s, o);
    __syncthreads();
    if (act && l == 0) red[w] = s;
    __syncthreads();
    if (act) {
      float gs = (t < Un) ? (red[0] + red[1]) : red[2];
      float r = e / gs;
      if (t < Un) out[(size_t)bx * Un + t] = r;
      else        out[(size_t)Bn * Un + (size_t)bx * Pn + (t - Un)] = r;
    }
  }
}

// ---------------------------------------------------------------------------
extern "C" void kernel_launch(void* const* d_in, const int* in_sizes, int n_in,
                              void* d_out, int out_size, void* d_ws, size_t ws_size,
                              hipStream_t stream) {
  const float* utt   = (const float*)d_in[0];  // [128,256,768]
  const float* ph    = (const float*)d_in[1];  // [64,256,768]
  const float* w_utt = (const float*)d_in[2];  // [128,128,64]
  const float* b_utt = (const float*)d_in[3];  // [128]
  const float* w_ph  = (const float*)d_in[4];  // [64,64,128]
  const float* b_ph  = (const float*)d_in[5];  // [64]

  char* ws = (char*)d_ws;
  ushort* Cbf     = (ushort*)(ws);                 // 256*128*64*2  = 4 MiB
  ushort* Wbf     = (ushort*)(ws + 4194304);       // 192*8192*2   = 3 MiB
  float*  partial = (float*)(ws + 7340032);        // 16*256*192*4 = 3 MiB

  // barrier counters: ws tail if it exists, else d_out head (fully
  // overwritten by C-part at the end of the kernel).
  unsigned* ctr = (ws_size >= 10485760 + 16)
                      ? (unsigned*)(ws + 10485760)
                      : (unsigned*)d_out;
  hipMemsetAsync(ctr, 0, 2 * sizeof(unsigned), stream);

  mega<<<dim3(NBLK), dim3(512), 0, stream>>>(utt, ph, w_utt, w_ph, b_utt, b_ph,
                                             Cbf, Wbf, partial, (float*)d_out,
                                             ctr);
}

// Round 7
// 208.923 us; speedup vs baseline: 2.8996x; 2.8996x over previous
//
#include <hip/hip_runtime.h>
#include <stdint.h>

// Shapes (fixed by the problem)
#define Bn 256
#define Un 128
#define Pn 64
#define Hn 768
#define Ototal 192   // 128 row-logit outputs + 64 col-logit outputs
#define KC 16        // split-K chunks in phase B (K=8192 -> 512 each)

#define LDB 72       // phaseB LDS row stride (ushorts): 144B = 9*16 (b128-aligned)

typedef short s4v __attribute__((ext_vector_type(4)));
typedef short s8v __attribute__((ext_vector_type(8)));
typedef float f4v __attribute__((ext_vector_type(4)));

__device__ __forceinline__ short f2bf(float x) {
  union { float f; uint32_t u; } c; c.f = x;
  uint32_t r = (c.u + 0x7fffu + ((c.u >> 16) & 1u)) >> 16;  // RNE
  return (short)(r & 0xffffu);
}

__device__ __forceinline__ float dot4(float4 v) {
  return v.x * v.x + v.y * v.y + v.z * v.z + v.w * v.w;
}

__device__ __forceinline__ s8v pack8(float4 x, float4 y) {
  s8v r;
  r[0] = f2bf(x.x); r[1] = f2bf(x.y); r[2] = f2bf(x.z); r[3] = f2bf(x.w);
  r[4] = f2bf(y.x); r[5] = f2bf(y.y); r[6] = f2bf(y.z); r[7] = f2bf(y.w);
  return r;
}

// async global->LDS, 16B per lane. LDS dest must be linear: base + lane*16.
__device__ __forceinline__ void gl16(const float* g, float* l) {
  __builtin_amdgcn_global_load_lds(
      (const __attribute__((address_space(1))) uint32_t*)g,
      (__attribute__((address_space(3))) uint32_t*)l, 16, 0, 0);
}

// ---------------------------------------------------------------------------
// Fused kernel: phaseA (cosine-sim, blocks 0..511) + convW (blocks 512..2623).
//
// phaseA v7 — global_load_lds + counted vmcnt (the r0/r2 convoy killer):
//  * stage raw f32 chunks (64 rows x 32 floats, u and p) straight to LDS via
//    global_load_lds width=16 — no VGPR round-trip (r3/r4/r5's spill killer).
//  * chunk c+1 issued at iter top, waited with s_waitcnt vmcnt(2) (NEVER 0)
//    + raw s_barrier: prefetch stays in flight ACROSS the barrier. This is
//    the one mechanism __syncthreads structurally forbids (it drains vmcnt).
//  * bf16 convert + sumsq moved to the consume side, from LDS-hot data.
//  * XOR swizzle BOTH sides (rule #21): gload_lds dest is linear, so the
//    GLOBAL source col-group is pre-swizzled (g ^ (row&7)) and fragment
//    reads apply the same XOR -> 2-way banks (free) instead of 16-way.
//    Swizzle permutes within a row only => per-row sumsq unaffected.
//  * XCD pairing: halves 0/1 of batch b -> blocks bx, bx+8 (same XCD), so
//    the shared p-panel's second read is an L2 hit.
// ---------------------------------------------------------------------------
__global__ void __launch_bounds__(512, 4) phaseAW(const float* __restrict__ utt,
                                                  const float* __restrict__ ph,
                                                  ushort* __restrict__ Cbf,
                                                  const float* __restrict__ w_utt,
                                                  const float* __restrict__ w_ph,
                                                  ushort* __restrict__ Wbf) {
  __shared__ __align__(16) char smem[33280];
  const int bx = blockIdx.x;
  const int t = threadIdx.x;

  if (bx >= 512) {
    if (bx < 2560) {
      // w_utt convert: 2048 blocks x 512 thr x 1 elem -> W'[o][k]=w_utt[o,i,j]
      int idx = (bx - 512) * 512 + t;             // 0 .. 128*8192-1
      Wbf[idx] = (ushort)f2bf(w_utt[idx]);
      return;
    }
    // w_ph transpose: 64 blocks, W'[128+oc][i*64+j] = w_ph[oc,j,i]
    float* tile = (float*)smem;                   // [j][i] 64 x 129 (+1 pad)
    const int oc = bx - 2560;
    const float* src = w_ph + (size_t)oc * 8192;  // [j][i] = 64 x 128
#pragma unroll
    for (int itr = 0; itr < 4; ++itr) {
      int idx = itr * 2048 + t * 4;               // 4 consecutive i of one j
      int j = idx >> 7, i = idx & 127;
      float4 v = *(const float4*)(src + idx);     // coalesced 16B
      tile[j * 129 + i + 0] = v.x;
      tile[j * 129 + i + 1] = v.y;
      tile[j * 129 + i + 2] = v.z;
      tile[j * 129 + i + 3] = v.w;
    }
    __syncthreads();
    const size_t obase = (size_t)(128 + oc) * 8192;
#pragma unroll
    for (int itr = 0; itr < 4; ++itr) {
      int k = itr * 2048 + t * 4;                 // k = i*64 + j
      int i = k >> 6, j = k & 63;
      s4v o4 = { f2bf(tile[(j + 0) * 129 + i]),
                 f2bf(tile[(j + 1) * 129 + i]),
                 f2bf(tile[(j + 2) * 129 + i]),
                 f2bf(tile[(j + 3) * 129 + i]) };
      *(s4v*)&Wbf[obase + k] = o4;                // coalesced 8B
    }
    return;
  }

  // ---- phaseA path (blocks 0..511) ----
  // LDS: uf[2][64*32] f32 (16KB) | pf[2][64*32] f32 (16KB) | inu[64] | inp[64]
  float (*uf)[64 * 32] = (float (*)[64 * 32])smem;
  float (*pf)[64 * 32] = (float (*)[64 * 32])(smem + 16384);
  float* s_inu = (float*)(smem + 32768);
  float* s_inp = (float*)(smem + 33024);

  const int b    = (bx & 7) | ((bx >> 4) << 3);   // XCD pairing
  const int half = (bx >> 3) & 1;
  const int w = t >> 6, l = t & 63;

  // staging: thread t owns row r, 16B col-group gsw (source pre-swizzled so
  // the LINEAR LDS dest t*16 holds logical group (t&7)^(r&7) of row r).
  const int r   = t >> 3;                         // 0..63
  const int gsw = (t & 7) ^ (r & 7);              // swizzled 16B-group 0..7

  const size_t rstride = (size_t)Bn * Hn;
  const float* ubase = utt + (size_t)b * Hn + (size_t)(half * 64 + r) * rstride + gsw * 4;
  const float* pbase = ph  + (size_t)b * Hn + (size_t)r * rstride + gsw * 4;
  float* u0d = uf[0] + t * 4;   // linear dest = wave base + lane*16  (m104)
  float* u1d = uf[1] + t * 4;
  float* p0d = pf[0] + t * 4;
  float* p1d = pf[1] + t * 4;

  // MFMA fragment geometry (identical mapping to the verified r0 kernel)
  const int m  = l & 15;
  const int g0 = (l >> 4) * 2;                    // logical 16B-group of frag
  const int g1 = g0 + 1;
  const int it = w & 3;                           // i-tile (16 rows)
  const int jp = w >> 2;                          // j-half (32 cols)
  const int Ra  = it * 16 + m;
  const int Rb0 = jp * 32 + m;
  const int Rb1 = Rb0 + 16;
  const int sa  = Ra  & 7;                        // row swizzle keys
  const int sb0 = Rb0 & 7;
  const int sb1 = Rb1 & 7;

  f4v zero4 = {0.f, 0.f, 0.f, 0.f};
  f4v acc0 = zero4, acc1 = zero4;
  float ssu = 0.f, ssp = 0.f;

  // prologue: chunk 0 in flight
  gl16(ubase, u0d);
  gl16(pbase, p0d);

#pragma unroll
  for (int c = 0; c < 24; ++c) {
    if (c < 23) {                    // issue chunk c+1 (stays in flight
      gl16(ubase + (c + 1) * 32, ((c + 1) & 1) ? u1d : u0d);   // across the
      gl16(pbase + (c + 1) * 32, ((c + 1) & 1) ? p1d : p0d);   // barrier)
      __builtin_amdgcn_sched_barrier(0);
      asm volatile("s_waitcnt vmcnt(2)" ::: "memory");  // chunk c landed
    } else {
      asm volatile("s_waitcnt vmcnt(0)" ::: "memory");
    }
    __builtin_amdgcn_s_barrier();    // raw: does NOT drain the c+1 loads
    __builtin_amdgcn_sched_barrier(0);

    const float* uB = uf[c & 1];
    const float* pB = pf[c & 1];
    // fragment reads with read-side XOR (matches source pre-swizzle)
    float4 fa0  = *(const float4*)(uB + Ra  * 32 + ((g0 ^ sa)  << 2));
    float4 fa1  = *(const float4*)(uB + Ra  * 32 + ((g1 ^ sa)  << 2));
    float4 fb00 = *(const float4*)(pB + Rb0 * 32 + ((g0 ^ sb0) << 2));
    float4 fb01 = *(const float4*)(pB + Rb0 * 32 + ((g1 ^ sb0) << 2));
    float4 fb10 = *(const float4*)(pB + Rb1 * 32 + ((g0 ^ sb1) << 2));
    float4 fb11 = *(const float4*)(pB + Rb1 * 32 + ((g1 ^ sb1) << 2));
    // sumsq from own staged 16B (swizzle is within-row => row sums exact)
    float4 su = *(const float4*)(uB + t * 4);
    float4 sp = *(const float4*)(pB + t * 4);
    ssu += dot4(su);
    ssp += dot4(sp);
    s8v af  = pack8(fa0, fa1);
    s8v bf0 = pack8(fb00, fb01);
    s8v bf1 = pack8(fb10, fb11);
    acc0 = __builtin_amdgcn_mfma_f32_16x16x32_bf16(af, bf0, acc0, 0, 0, 0);
    acc1 = __builtin_amdgcn_mfma_f32_16x16x32_bf16(af, bf1, acc1, 0, 0, 0);

    asm volatile("s_waitcnt lgkmcnt(0)" ::: "memory");  // LDS reads done
    __builtin_amdgcn_s_barrier();    // safe to overwrite buf next iter
    __builtin_amdgcn_sched_barrier(0);
  }

  // row sumsq reductions: 8 threads/row are adjacent lanes
  ssu += __shfl_xor(ssu, 4); ssu += __shfl_xor(ssu, 2); ssu += __shfl_xor(ssu, 1);
  ssp += __shfl_xor(ssp, 4); ssp += __shfl_xor(ssp, 2); ssp += __shfl_xor(ssp, 1);
  if ((t & 7) == 0) {
    s_inu[r] = 1.f / fmaxf(sqrtf(ssu), 1e-8f);
    s_inp[r] = 1.f / fmaxf(sqrtf(ssp), 1e-8f);
  }
  __syncthreads();

  // epilogue: scale, store bf16 C[b][half*64+i][j]
  // D layout (verified m89/m91): col = lane&15, row = (lane>>4)*4 + reg
  const int cl = l & 15;
  const int rq = (l >> 4) * 4;
#pragma unroll
  for (int jt = 0; jt < 2; ++jt) {
    int j = jp * 32 + jt * 16 + cl;
    float sj = s_inp[j];
    f4v a = (jt == 0) ? acc0 : acc1;
#pragma unroll
    for (int rr = 0; rr < 4; ++rr) {
      int il = it * 16 + rq + rr;     // local row 0..63
      float v = a[rr] * s_inu[il] * sj;
      Cbf[((size_t)b * Un + half * 64 + il) * Pn + j] = (ushort)f2bf(v);
    }
  }
}

// ---------------------------------------------------------------------------
// Kernel 3: logits GEMM, M=256, N=192, K=8192, split-K (KC=16).
// ---------------------------------------------------------------------------
__global__ void __launch_bounds__(256) phaseB(const ushort* __restrict__ Cbf,
                                              const ushort* __restrict__ Wbf,
                                              float* __restrict__ partial) {
  const int kc = blockIdx.x;
  const int mt = blockIdx.y;
  const int nt = blockIdx.z;
  const int t = threadIdx.x;
  const int w = t >> 6, l = t & 63;

  __shared__ short Ab[64 * LDB];
  __shared__ short Bb[64 * LDB];

  const int row = t >> 2;          // 0..63
  const int k16 = (t & 3) * 16;    // 16 elems per thread per stage-row

  f4v zero4 = {0.f, 0.f, 0.f, 0.f};
  f4v acc[4] = {zero4, zero4, zero4, zero4};

  const ushort* Ag = Cbf + (size_t)(mt * 64 + row) * 8192 + kc * 512 + k16;
  const ushort* Bg = Wbf + (size_t)(nt * 64 + row) * 8192 + kc * 512 + k16;
  const int m  = l & 15;
  const int ko = (l >> 4) * 8;

  for (int c = 0; c < 8; ++c) {
    s8v av0 = *(const s8v*)(Ag + c * 64);
    s8v av1 = *(const s8v*)(Ag + c * 64 + 8);
    s8v bv0 = *(const s8v*)(Bg + c * 64);
    s8v bv1 = *(const s8v*)(Bg + c * 64 + 8);
    __syncthreads();
    *(s8v*)&Ab[row * LDB + k16]     = av0;
    *(s8v*)&Ab[row * LDB + k16 + 8] = av1;
    *(s8v*)&Bb[row * LDB + k16]     = bv0;
    *(s8v*)&Bb[row * LDB + k16 + 8] = bv1;
    __syncthreads();
#pragma unroll
    for (int ks = 0; ks < 2; ++ks) {
      s8v af = *(const s8v*)&Ab[(16 * w + m) * LDB + ks * 32 + ko];
#pragma unroll
      for (int jt = 0; jt < 4; ++jt) {
        s8v bf = *(const s8v*)&Bb[(16 * jt + m) * LDB + ks * 32 + ko];
        acc[jt] = __builtin_amdgcn_mfma_f32_16x16x32_bf16(af, bf, acc[jt], 0, 0, 0);
      }
    }
  }

  const int rq = (l >> 4) * 4;
#pragma unroll
  for (int jt = 0; jt < 4; ++jt) {
    int og = nt * 64 + 16 * jt + (l & 15);
#pragma unroll
    for (int r = 0; r < 4; ++r) {
      int bg = mt * 64 + 16 * w + rq + r;
      partial[((size_t)kc * Bn + bg) * Ototal + og] = acc[jt][r];
    }
  }
}

// ---------------------------------------------------------------------------
// Kernel 4: reduce split-K partials + bias + dual-group softmax.
// ---------------------------------------------------------------------------
__global__ void __launch_bounds__(192) phaseC(const float* __restrict__ partial,
                                              const float* __restrict__ b_utt,
                                              const float* __restrict__ b_ph,
                                              float* __restrict__ out) {
  const int b = blockIdx.x;
  const int t = threadIdx.x;      // 0..191
  const int w = t >> 6, l = t & 63;

  float v = 0.f;
#pragma unroll
  for (int kc = 0; kc < KC; ++kc)
    v += partial[((size_t)kc * Bn + b) * Ototal + t];
  v += (t < Un) ? b_utt[t] : b_ph[t - Un];

  __shared__ float red[3];
  float mx = v;
  for (int o = 32; o >= 1; o >>= 1) mx = fmaxf(mx, __shfl_xor(mx, o));
  if (l == 0) red[w] = mx;
  __syncthreads();
  float gmax = (t < Un) ? fmaxf(red[0], red[1]) : red[2];
  float e = expf(v - gmax);
  float s = e;
  for (int o = 32; o >= 1; o >>= 1) s += __shfl_xor(s, o);
  __syncthreads();
  if (l == 0) red[w] = s;
  __syncthreads();
  float gs = (t < Un) ? (red[0] + red[1]) : red[2];
  float r = e / gs;
  if (t < Un) out[(size_t)b * Un + t] = r;
  else        out[(size_t)Bn * Un + (size_t)b * Pn + (t - Un)] = r;
}

// ---------------------------------------------------------------------------
extern "C" void kernel_launch(void* const* d_in, const int* in_sizes, int n_in,
                              void* d_out, int out_size, void* d_ws, size_t ws_size,
                              hipStream_t stream) {
  const float* utt   = (const float*)d_in[0];  // [128,256,768]
  const float* ph    = (const float*)d_in[1];  // [64,256,768]
  const float* w_utt = (const float*)d_in[2];  // [128,128,64]
  const float* b_utt = (const float*)d_in[3];  // [128]
  const float* w_ph  = (const float*)d_in[4];  // [64,64,128]
  const float* b_ph  = (const float*)d_in[5];  // [64]

  char* ws = (char*)d_ws;
  ushort* Cbf     = (ushort*)(ws);                 // 256*128*64*2  = 4 MiB
  ushort* Wbf     = (ushort*)(ws + 4194304);       // 192*8192*2   = 3 MiB
  float*  partial = (float*)(ws + 7340032);        // 16*256*192*4 = 3 MiB

  phaseAW<<<dim3(2624), dim3(512), 0, stream>>>(utt, ph, Cbf, w_utt, w_ph, Wbf);
  phaseB <<<dim3(KC, 4, 3), dim3(256), 0, stream>>>(Cbf, Wbf, partial);
  phaseC <<<dim3(Bn), dim3(192), 0, stream>>>(partial, b_utt, b_ph, (float*)d_out);
}